// Round 3
// baseline (278.643 us; speedup 1.0000x reference)
//
#include <hip/hip_runtime.h>
#include <hip/hip_bf16.h>
#include <math.h>

// Problem constants
#define BB 8
#define CC 256
#define TT 8192
#define EPSF 1e-5f

typedef short v8s __attribute__((ext_vector_type(8)));
typedef float v4f __attribute__((ext_vector_type(4)));

#define MFMA(a, b, c) __builtin_amdgcn_mfma_f32_16x16x32_bf16((a), (b), (c), 0, 0, 0)

// MFMA 16x16x32 bf16 fragment conventions (m89/m91 verified):
//   A[m][k]: m = lane&15, k = (lane>>4)*8 + j   (8 contiguous k per lane)
//   B[k][n]: n = lane&15, k = (lane>>4)*8 + j
//   C/D:     col = lane&15, row = (lane>>4)*4 + reg

// Workspace layout (float offsets). Total ~51.8 MB.
#define OFF_XT 0               // xT bf16 [b][t][c] = 16,777,216 ushort
#define OFF_WKV 8388608        // Wkv bf16 [h][type][64][256] = 131072 ushort
#define OFF_WPJ 8454144        // Wproj bf16 [256][256] = 65536 ushort
#define OFF_ZPART 8486912      // fp32 [512 blk][256]
#define OFF_KV 8617984         // fp32 [b][h][64][64]
#define OFF_UPART 8749056      // bf16 [512 blk][4h][64][64] = 8,388,608 ushort
#define OFF_PT 8749056         // (overlays UPART; UPART dead after k2) bf16 [b][c][256]
#define OFF_MBF 9011200        // bf16 [b][o][c]

__device__ __forceinline__ unsigned short f2bf(float f) {
  __hip_bfloat16 h = __float2bfloat16(f);
  return __builtin_bit_cast(unsigned short, h);
}
__device__ __forceinline__ float bf2f(unsigned short u) {
  return __bfloat162float(__builtin_bit_cast(__hip_bfloat16, u));
}

// Async global->LDS DMA, 16 B/lane. LDS dest = wave-uniform base + lane*16.
__device__ __forceinline__ void ldscpy16(unsigned short* lds_base,
                                         const unsigned short* g_lane) {
  __builtin_amdgcn_global_load_lds(
      (const __attribute__((address_space(1))) unsigned int*)(const void*)g_lane,
      (__attribute__((address_space(3))) unsigned int*)(void*)lds_base, 16, 0, 0);
}

// Swizzled xs layout (ushort offsets): t-pair p at p*520; row t at
// p*520 + (t&1)*256 + c. Bank base for B-frag reads = 4*(cl>>1)+4q -> conflict-free.
#define XS_ADDR(t, c) ((((t) >> 1) * 520) + (((t)&1) * 256) + (c))

// ---------------------------------------------------------------------------
// kT: x fp32 [b][c][t] -> xT bf16 [b][t][c]. 64x64 tiles via LDS.
// ---------------------------------------------------------------------------
__global__ __launch_bounds__(256) void kT_transpose(const float* __restrict__ x,
                                                    float* __restrict__ ws) {
  __shared__ float lsx[64 * 65];
  const int bi = blockIdx.x;  // 8 b * 4 cseg * 128 tseg
  const int b = bi >> 9;
  const int cseg = (bi >> 7) & 3;
  const int tseg = bi & 127;
  const int c0 = cseg * 64, t0 = tseg * 64;
  const int tid = threadIdx.x;
  {
    const int cl = tid >> 2, q4 = tid & 3;
    const float* xp = x + (size_t)b * CC * TT + (size_t)(c0 + cl) * TT + t0 + q4 * 16;
#pragma unroll
    for (int j = 0; j < 4; ++j) {
      const float4 v = reinterpret_cast<const float4*>(xp)[j];
      float* d = &lsx[cl * 65 + q4 * 16 + j * 4];
      d[0] = v.x; d[1] = v.y; d[2] = v.z; d[3] = v.w;
    }
  }
  __syncthreads();
  {
    const int tl = tid >> 2, cs = tid & 3;
    unsigned short ub[16];
#pragma unroll
    for (int j = 0; j < 16; ++j) ub[j] = f2bf(lsx[(cs * 16 + j) * 65 + tl]);
    unsigned short* xt = (unsigned short*)(ws + OFF_XT) +
                         ((size_t)b * TT + t0 + tl) * 256 + c0 + cs * 16;
    reinterpret_cast<int4*>(xt)[0] = *reinterpret_cast<int4*>(&ub[0]);
    reinterpret_cast<int4*>(xt)[1] = *reinterpret_cast<int4*>(&ub[8]);
  }
}

// ---------------------------------------------------------------------------
// k0: pack weights to bf16. rows 0..511: Wkv[h][type][d][c]; 512..767: Wproj.
// ---------------------------------------------------------------------------
__global__ void k0_pack(const float* __restrict__ Wpre,
                        const float* __restrict__ Wproj,
                        float* __restrict__ ws) {
  const int r = blockIdx.x;
  const int c = threadIdx.x;
  if (r < 512) {
    const int h = r >> 7, type = (r >> 6) & 1, d = r & 63;
    const int src = h * 192 + 64 + type * 64 + d;
    ((unsigned short*)(ws + OFF_WKV))[r * 256 + c] = f2bf(Wpre[(size_t)src * 256 + c]);
  } else {
    const int rr = r - 512;
    ((unsigned short*)(ws + OFF_WPJ))[rr * 256 + c] = f2bf(Wproj[(size_t)rr * 256 + c]);
  }
}

// ---------------------------------------------------------------------------
// k1: per (b, 128-t chunk), 8 waves = 4 heads x {k,v}. Per 64-t sub:
// DMA xT chunk -> swizzled LDS; MFMA k/v; exp (softmax is shift-invariant;
// no max pass); e/v round-trip through LDS (pitch 40); MFMA U += e @ v^T.
// Partials: U bf16, Z fp32 per block.
// ---------------------------------------------------------------------------
__global__ __launch_bounds__(512, 4) void k1_kv(float* __restrict__ ws) {
  // xs (32 pairs * 520 = 16640 ushort) overlaid by e/v buffers
  // (4 heads x (64x40 ek + 64x40 v) = 20480 ushort = 40 KiB)
  __shared__ unsigned short lds[20480];

  const int tid = threadIdx.x;
  const int w = tid >> 6, lane = tid & 63, q = lane >> 4, cl = lane & 15;
  const int h = w >> 1, type = w & 1;
  const int bi = blockIdx.x;  // 512 = 8 b * 64 chunks
  const int b = bi >> 6, chunk = bi & 63;
  const int t0 = chunk * 128;
  const unsigned short* xT =
      (const unsigned short*)(ws + OFF_XT) + (size_t)b * TT * 256;
  const unsigned short* wkv =
      (const unsigned short*)(ws + OFF_WKV) + (size_t)((h * 2 + type) * 64) * 256;
  unsigned short* ekb = &lds[h * 5120];         // ek[64][40]
  unsigned short* vbb = &lds[h * 5120 + 2560];  // v [64][40]

  v4f Uacc[2][4];
#pragma unroll
  for (int i = 0; i < 2; ++i)
#pragma unroll
    for (int j = 0; j < 4; ++j) Uacc[i][j] = (v4f){0.f, 0.f, 0.f, 0.f};
  float zacc[4][4];
#pragma unroll
  for (int i = 0; i < 4; ++i)
#pragma unroll
    for (int j = 0; j < 4; ++j) zacc[i][j] = 0.f;

  for (int sub = 0; sub < 2; ++sub) {
    // ---- async stage 64 t x 256 c bf16: 32 pair-loads, 4 per wave ----
    {
      const unsigned short* xsrc = xT + (size_t)(t0 + sub * 64) * 256 + lane * 8;
#pragma unroll
      for (int i = 0; i < 4; ++i) {
        const int pair = w * 4 + i;
        ldscpy16(&lds[pair * 520], xsrc + pair * 512);
      }
    }
    __syncthreads();  // drains vmcnt (DMA) + protects e/v region reuse

    // ---- phase A: rows = this wave's 64 k- or v-rows, cols = 64 t ----
    v4f acc[4][4];
#pragma unroll
    for (int i = 0; i < 4; ++i)
#pragma unroll
      for (int j = 0; j < 4; ++j) acc[i][j] = (v4f){0.f, 0.f, 0.f, 0.f};
#pragma unroll
    for (int ks = 0; ks < 8; ++ks) {
      v8s af[4], bfu[4];
#pragma unroll
      for (int rt = 0; rt < 4; ++rt)
        af[rt] = *(const v8s*)(wkv + (size_t)(rt * 16 + cl) * 256 + ks * 32 + q * 8);
#pragma unroll
      for (int ct = 0; ct < 4; ++ct) {
        const int t = ct * 16 + cl;
        bfu[ct] = *(const v8s*)&lds[XS_ADDR(t, ks * 32 + q * 8)];
      }
#pragma unroll
      for (int rt = 0; rt < 4; ++rt)
#pragma unroll
        for (int ct = 0; ct < 4; ++ct)
          acc[rt][ct] = MFMA(af[rt], bfu[ct], acc[rt][ct]);
    }
    __syncthreads();  // all waves done with xs; e/v buffers overlay it

    // ---- phase B: two 32-t halves through LDS (pitch 40) ----
#pragma unroll
    for (int hp = 0; hp < 2; ++hp) {
      if (type == 0) {
#pragma unroll
        for (int rt = 0; rt < 4; ++rt)
#pragma unroll
          for (int cc = 0; cc < 2; ++cc) {
            const int ct = hp * 2 + cc;
#pragma unroll
            for (int reg = 0; reg < 4; ++reg) {
              const float e = __expf(acc[rt][ct][reg]);
              zacc[rt][reg] += e;
              ekb[(rt * 16 + q * 4 + reg) * 40 + cc * 16 + cl] = f2bf(e);
            }
          }
      } else {
#pragma unroll
        for (int rt = 0; rt < 4; ++rt)
#pragma unroll
          for (int cc = 0; cc < 2; ++cc) {
            const int ct = hp * 2 + cc;
#pragma unroll
            for (int reg = 0; reg < 4; ++reg)
              vbb[(rt * 16 + q * 4 + reg) * 40 + cc * 16 + cl] =
                  f2bf(acc[rt][ct][reg]);
          }
      }
      __syncthreads();  // head's wave pair exchanges e/v
      {
        const int du0 = type * 32;  // k-wave: U rows 0..31, v-wave: 32..63
        v8s afu[2], bfu[4];
#pragma unroll
        for (int ur = 0; ur < 2; ++ur)
          afu[ur] = *(const v8s*)&ekb[(du0 + ur * 16 + cl) * 40 + q * 8];
#pragma unroll
        for (int uc = 0; uc < 4; ++uc)
          bfu[uc] = *(const v8s*)&vbb[(uc * 16 + cl) * 40 + q * 8];
#pragma unroll
        for (int ur = 0; ur < 2; ++ur)
#pragma unroll
          for (int uc = 0; uc < 4; ++uc)
            Uacc[ur][uc] = MFMA(afu[ur], bfu[uc], Uacc[ur][uc]);
      }
      __syncthreads();  // half-1 / next sub will overwrite buffers
    }
  }

  // ---- Z: butterfly over the 16 col-lanes, store from cl==0 ----
  if (type == 0) {
#pragma unroll
    for (int m = 1; m < 16; m <<= 1)
#pragma unroll
      for (int rt = 0; rt < 4; ++rt)
#pragma unroll
        for (int reg = 0; reg < 4; ++reg)
          zacc[rt][reg] += __shfl_xor(zacc[rt][reg], m, 64);
    if (cl == 0) {
      for (int rt = 0; rt < 4; ++rt)
        for (int reg = 0; reg < 4; ++reg)
          ws[OFF_ZPART + (size_t)bi * 256 + h * 64 + rt * 16 + q * 4 + reg] =
              zacc[rt][reg];
    }
  }
  // ---- U partial store (bf16) ----
  unsigned short* Up =
      (unsigned short*)(ws + OFF_UPART) + (size_t)bi * 16384 + h * 4096;
#pragma unroll
  for (int ur = 0; ur < 2; ++ur)
#pragma unroll
    for (int uc = 0; uc < 4; ++uc)
#pragma unroll
      for (int reg = 0; reg < 4; ++reg)
        Up[(type * 32 + ur * 16 + q * 4 + reg) * 64 + uc * 16 + cl] =
            f2bf(Uacc[ur][uc][reg]);
}

// ---------------------------------------------------------------------------
// k2: reduce 64 partial blocks per batch; kv = U / Z[d].
// ---------------------------------------------------------------------------
__global__ void k2_reduce_kv(float* __restrict__ ws) {
  const int bi = blockIdx.x;  // 0..511
  const int bh = bi >> 4, j = bi & 15;
  const int b = bh >> 2, h = bh & 3;
  const int tid = threadIdx.x;

  __shared__ float zinv[64];
  if (tid < 64) {
    float z = 0.f;
    for (int cb = 0; cb < 64; ++cb)
      z += ws[OFF_ZPART + (size_t)(b * 64 + cb) * 256 + h * 64 + tid];
    zinv[tid] = 1.0f / z;
  }
  __syncthreads();

  const int idx = j * 256 + tid;  // 0..4095 in (b,h)
  const int d = idx >> 6;
  const unsigned short* up = (const unsigned short*)(ws + OFF_UPART);
  float s = 0.f;
  for (int cb = 0; cb < 64; ++cb)
    s += bf2f(up[(size_t)(b * 64 + cb) * 16384 + h * 4096 + idx]);
  ws[OFF_KV + (size_t)(b * 4 + h) * 4096 + idx] = s * zinv[d];
}

// ---------------------------------------------------------------------------
// k3a: P^T[b][c][h*64+e] = sum_d kv[b,h,d,e] * Wq[h*192+d][c]  (bf16)
// ---------------------------------------------------------------------------
__global__ void k3a_P(const float* __restrict__ Wpre, float* __restrict__ ws) {
  const int bi = blockIdx.x;  // b*256 + he
  const int b = bi >> 8, he = bi & 255;
  const int h = he >> 6, e = he & 63;
  const int c = threadIdx.x;
  const float* kvp = ws + OFF_KV + (size_t)(b * 4 + h) * 4096;
  float acc = 0.f;
#pragma unroll 8
  for (int d = 0; d < 64; ++d)
    acc += kvp[d * 64 + e] * Wpre[(size_t)(h * 192 + d) * 256 + c];
  ((unsigned short*)(ws + OFF_PT))[(size_t)b * 65536 + (size_t)c * 256 + he] =
      f2bf(acc);
}

// ---------------------------------------------------------------------------
// k3b: M[b][o][c] = scale * (Wproj @ P) via MFMA; grid = 8b x 4 c-groups.
// ---------------------------------------------------------------------------
__global__ __launch_bounds__(256, 2) void k3b_M(const float* __restrict__ scale,
                                                float* __restrict__ ws) {
  const int bi = blockIdx.x, b = bi >> 2, cg = bi & 3;
  const int tid = threadIdx.x, w = tid >> 6, lane = tid & 63, q = lane >> 4,
            cl = lane & 15;
  const unsigned short* wpj = (const unsigned short*)(ws + OFF_WPJ);
  const unsigned short* pt =
      (const unsigned short*)(ws + OFF_PT) + (size_t)b * 65536;
  v4f acc[4][4];
#pragma unroll
  for (int i = 0; i < 4; ++i)
#pragma unroll
    for (int j = 0; j < 4; ++j) acc[i][j] = (v4f){0.f, 0.f, 0.f, 0.f};
#pragma unroll
  for (int ks = 0; ks < 8; ++ks) {
    v8s af[4], bfu[4];
#pragma unroll
    for (int rt = 0; rt < 4; ++rt)
      af[rt] = *(const v8s*)(wpj + (size_t)(w * 64 + rt * 16 + cl) * 256 +
                             ks * 32 + q * 8);
#pragma unroll
    for (int ct = 0; ct < 4; ++ct)
      bfu[ct] = *(const v8s*)(pt + (size_t)(cg * 64 + ct * 16 + cl) * 256 +
                              ks * 32 + q * 8);
#pragma unroll
    for (int rt = 0; rt < 4; ++rt)
#pragma unroll
      for (int ct = 0; ct < 4; ++ct)
        acc[rt][ct] = MFMA(af[rt], bfu[ct], acc[rt][ct]);
  }
  const float s = scale[0];
  unsigned short* mbf = (unsigned short*)(ws + OFF_MBF);
#pragma unroll
  for (int rt = 0; rt < 4; ++rt)
#pragma unroll
    for (int ct = 0; ct < 4; ++ct)
#pragma unroll
      for (int reg = 0; reg < 4; ++reg) {
        const int o = w * 64 + rt * 16 + q * 4 + reg;
        const int c = cg * 64 + ct * 16 + cl;
        mbf[((size_t)b * 256 + o) * 256 + c] = f2bf(s * acc[rt][ct][reg]);
      }
}

// ---------------------------------------------------------------------------
// k4: out = LN_C( M@x + scale*b_proj + x ) * gamma + beta. Async xT staging,
// MFMA, fused LN. Grid: 8b x 128 chunks of 64 t; 4 waves.
// ---------------------------------------------------------------------------
__global__ __launch_bounds__(256, 4) void k4_proj_ln(
    const float* __restrict__ bproj, const float* __restrict__ scale,
    const float* __restrict__ gamma, const float* __restrict__ beta,
    const float* __restrict__ ws, float* __restrict__ out) {
  __shared__ unsigned short xs[16640];  // swizzled [64 t][256 c]
  __shared__ float red1[256], red2[256], muA[64], rsA[64];
  const int bi = blockIdx.x, b = bi >> 7, tc = bi & 127;
  const int tg0 = tc * 64;
  const int tid = threadIdx.x, w = tid >> 6, lane = tid & 63, q = lane >> 4,
            cl = lane & 15;

  // async stage xT[tg0..+64)[c] -> xs: 32 pair-loads, 8 per wave
  {
    const unsigned short* xsrc = (const unsigned short*)(ws + OFF_XT) +
                                 ((size_t)b * TT + tg0) * 256 + lane * 8;
#pragma unroll
    for (int i = 0; i < 8; ++i) {
      const int pair = w * 8 + i;
      ldscpy16(&xs[pair * 520], xsrc + pair * 512);
    }
  }
  __syncthreads();

  const unsigned short* mbf =
      (const unsigned short*)(ws + OFF_MBF) + (size_t)b * 65536;
  v4f acc[4][4];
#pragma unroll
  for (int i = 0; i < 4; ++i)
#pragma unroll
    for (int j = 0; j < 4; ++j) acc[i][j] = (v4f){0.f, 0.f, 0.f, 0.f};
#pragma unroll
  for (int ks = 0; ks < 8; ++ks) {
    v8s af[4], bfu[4];
#pragma unroll
    for (int rt = 0; rt < 4; ++rt)
      af[rt] = *(const v8s*)(mbf + (size_t)(w * 64 + rt * 16 + cl) * 256 +
                             ks * 32 + q * 8);
#pragma unroll
    for (int ct = 0; ct < 4; ++ct) {
      const int t = ct * 16 + cl;
      bfu[ct] = *(const v8s*)&xs[XS_ADDR(t, ks * 32 + q * 8)];
    }
#pragma unroll
    for (int rt = 0; rt < 4; ++rt)
#pragma unroll
      for (int ct = 0; ct < 4; ++ct)
        acc[rt][ct] = MFMA(af[rt], bfu[ct], acc[rt][ct]);
  }

  // y = ctx_proj + scale*b_proj + residual (residual from bf16 xs)
  const float s = scale[0];
#pragma unroll
  for (int rt = 0; rt < 4; ++rt)
#pragma unroll
    for (int reg = 0; reg < 4; ++reg) {
      const int o = w * 64 + rt * 16 + q * 4 + reg;
      const float sb = s * bproj[o];
#pragma unroll
      for (int ct = 0; ct < 4; ++ct) {
        const int tl = ct * 16 + cl;
        acc[rt][ct][reg] += sb + bf2f(xs[XS_ADDR(tl, o)]);
      }
    }

  // LN sums over C: per-lane 16 rows -> butterfly over q -> cross-wave LDS
#pragma unroll
  for (int ct = 0; ct < 4; ++ct) {
    float s1 = 0.f, s2 = 0.f;
#pragma unroll
    for (int rt = 0; rt < 4; ++rt)
#pragma unroll
      for (int reg = 0; reg < 4; ++reg) {
        const float v = acc[rt][ct][reg];
        s1 += v;
        s2 += v * v;
      }
    s1 += __shfl_xor(s1, 16, 64);
    s1 += __shfl_xor(s1, 32, 64);
    s2 += __shfl_xor(s2, 16, 64);
    s2 += __shfl_xor(s2, 32, 64);
    if (q == 0) {
      red1[w * 64 + ct * 16 + cl] = s1;
      red2[w * 64 + ct * 16 + cl] = s2;
    }
  }
  __syncthreads();
  if (tid < 64) {
    const float s1 = red1[tid] + red1[64 + tid] + red1[128 + tid] + red1[192 + tid];
    const float s2 = red2[tid] + red2[64 + tid] + red2[128 + tid] + red2[192 + tid];
    const float mu = s1 * (1.f / 256.f);
    const float var = s2 * (1.f / 256.f) - mu * mu;
    muA[tid] = mu;
    rsA[tid] = rsqrtf(var + EPSF);
  }
  __syncthreads();

  float* ob = out + (size_t)b * (CC * TT) + tg0;
#pragma unroll
  for (int rt = 0; rt < 4; ++rt)
#pragma unroll
    for (int reg = 0; reg < 4; ++reg) {
      const int o = w * 64 + rt * 16 + q * 4 + reg;
      const float g = gamma[o], bt = beta[o];
#pragma unroll
      for (int ct = 0; ct < 4; ++ct) {
        const int tl = ct * 16 + cl;
        ob[(size_t)o * TT + tl] = (acc[rt][ct][reg] - muA[tl]) * rsA[tl] * g + bt;
      }
    }
}

// ---------------------------------------------------------------------------
extern "C" void kernel_launch(void* const* d_in, const int* in_sizes, int n_in,
                              void* d_out, int out_size, void* d_ws,
                              size_t ws_size, hipStream_t stream) {
  (void)in_sizes; (void)n_in; (void)out_size; (void)ws_size;
  const float* x = (const float*)d_in[0];
  const float* Wpre = (const float*)d_in[1];
  const float* Wproj = (const float*)d_in[2];
  const float* bproj = (const float*)d_in[3];
  const float* scale = (const float*)d_in[4];
  const float* gamma = (const float*)d_in[5];
  const float* beta = (const float*)d_in[6];
  float* out = (float*)d_out;
  float* ws = (float*)d_ws;

  hipLaunchKernelGGL(kT_transpose, dim3(4096), dim3(256), 0, stream, x, ws);
  hipLaunchKernelGGL(k0_pack, dim3(768), dim3(256), 0, stream, Wpre, Wproj, ws);
  hipLaunchKernelGGL(k1_kv, dim3(512), dim3(512), 0, stream, ws);
  hipLaunchKernelGGL(k2_reduce_kv, dim3(512), dim3(256), 0, stream, ws);
  hipLaunchKernelGGL(k3a_P, dim3(BB * 256), dim3(256), 0, stream, Wpre, ws);
  hipLaunchKernelGGL(k3b_M, dim3(32), dim3(256), 0, stream, scale, ws);
  hipLaunchKernelGGL(k4_proj_ln, dim3(BB * 128), dim3(256), 0, stream, bproj,
                     scale, gamma, beta, ws, out);
}

// Round 4
// 228.598 us; speedup vs baseline: 1.2189x; 1.2189x over previous
//
#include <hip/hip_runtime.h>
#include <hip/hip_bf16.h>
#include <math.h>

// Problem constants
#define BB 8
#define CC 256
#define TT 8192
#define EPSF 1e-5f

typedef short v8s __attribute__((ext_vector_type(8)));
typedef float v4f __attribute__((ext_vector_type(4)));

#define MFMA(a, b, c) __builtin_amdgcn_mfma_f32_16x16x32_bf16((a), (b), (c), 0, 0, 0)

// MFMA 16x16x32 bf16 fragment conventions (m89/m91 verified):
//   A[m][k]: m = lane&15, k = (lane>>4)*8 + j   (8 contiguous k per lane)
//   B[k][n]: n = lane&15, k = (lane>>4)*8 + j
//   C/D:     col = lane&15, row = (lane>>4)*4 + reg
//
// xT global layout is XOR-swizzled at 16-B chunk granularity: chunk j (8 bf16)
// of row t lives at slot (j ^ (t&7)). DMA (wave-uniform base + lane*16) copies
// rows verbatim; LDS B-frag reads at slot ((ks*4+q)^(t&7)) are conflict-free
// (8-lane service group covers all 8 4-bank groups).

// Workspace layout (float offsets). Total ~51.8 MB.
#define OFF_XT 0               // xT bf16 swizzled [b][t][256c] = 16,777,216 ushort
#define OFF_WKV 8388608        // Wkv bf16 [h][type][64][256] = 131072 ushort
#define OFF_WPJ 8454144        // Wproj bf16 [256][256] = 65536 ushort
#define OFF_ZPART 8486912      // fp32 [512 blk][256]
#define OFF_KV 8617984         // fp32 [b][h][64][64]
#define OFF_UPART 8749056      // bf16 [512 blk][4h][64][64] = 8,388,608 ushort
#define OFF_PT 8749056         // (overlays UPART; dead after k2) bf16 [b][c][256]
#define OFF_MBF 9011200        // bf16 [b][o][c]

__device__ __forceinline__ unsigned short f2bf(float f) {
  __hip_bfloat16 h = __float2bfloat16(f);
  return __builtin_bit_cast(unsigned short, h);
}
__device__ __forceinline__ float bf2f(unsigned short u) {
  return __bfloat162float(__builtin_bit_cast(__hip_bfloat16, u));
}

// Async global->LDS DMA, 16 B/lane. LDS dest = wave-uniform base + lane*16.
__device__ __forceinline__ void ldscpy16(unsigned short* lds_base,
                                         const unsigned short* g_lane) {
  __builtin_amdgcn_global_load_lds(
      (const __attribute__((address_space(1))) unsigned int*)(const void*)g_lane,
      (__attribute__((address_space(3))) unsigned int*)(void*)lds_base, 16, 0, 0);
}

// ---------------------------------------------------------------------------
// kT: x fp32 [b][c][t] -> xT bf16 [b][t][c] with per-row XOR chunk swizzle.
// ---------------------------------------------------------------------------
__global__ __launch_bounds__(256) void kT_transpose(const float* __restrict__ x,
                                                    float* __restrict__ ws) {
  __shared__ float lsx[64 * 65];
  const int bi = blockIdx.x;  // 8 b * 4 cseg * 128 tseg
  const int b = bi >> 9;
  const int cseg = (bi >> 7) & 3;
  const int tseg = bi & 127;
  const int c0 = cseg * 64, t0 = tseg * 64;
  const int tid = threadIdx.x;
  {
    const int cl = tid >> 2, q4 = tid & 3;
    const float* xp = x + (size_t)b * CC * TT + (size_t)(c0 + cl) * TT + t0 + q4 * 16;
#pragma unroll
    for (int j = 0; j < 4; ++j) {
      const float4 v = reinterpret_cast<const float4*>(xp)[j];
      float* d = &lsx[cl * 65 + q4 * 16 + j * 4];
      d[0] = v.x; d[1] = v.y; d[2] = v.z; d[3] = v.w;
    }
  }
  __syncthreads();
  {
    const int tl = tid >> 2, cs = tid & 3;
    unsigned short ub[16];
#pragma unroll
    for (int j = 0; j < 16; ++j) ub[j] = f2bf(lsx[(cs * 16 + j) * 65 + tl]);
    unsigned short* xrow =
        (unsigned short*)(ws + OFF_XT) + ((size_t)b * TT + t0 + tl) * 256;
    const int m = tl & 7;
    const int j0 = cseg * 8 + cs * 2;
    *reinterpret_cast<int4*>(xrow + ((j0 + 0) ^ m) * 8) =
        *reinterpret_cast<int4*>(&ub[0]);
    *reinterpret_cast<int4*>(xrow + ((j0 + 1) ^ m) * 8) =
        *reinterpret_cast<int4*>(&ub[8]);
  }
}

// ---------------------------------------------------------------------------
// k0: pack weights to bf16. rows 0..511: Wkv[h][type][d][c]; 512..767: Wproj.
// ---------------------------------------------------------------------------
__global__ void k0_pack(const float* __restrict__ Wpre,
                        const float* __restrict__ Wproj,
                        float* __restrict__ ws) {
  const int r = blockIdx.x;
  const int c = threadIdx.x;
  if (r < 512) {
    const int h = r >> 7, type = (r >> 6) & 1, d = r & 63;
    const int src = h * 192 + 64 + type * 64 + d;
    ((unsigned short*)(ws + OFF_WKV))[r * 256 + c] = f2bf(Wpre[(size_t)src * 256 + c]);
  } else {
    const int rr = r - 512;
    ((unsigned short*)(ws + OFF_WPJ))[rr * 256 + c] = f2bf(Wproj[(size_t)rr * 256 + c]);
  }
}

// ---------------------------------------------------------------------------
// k1: per (b, 128-t chunk), 8 waves = 4 heads x {k,v}. Per 64-t sub:
// DMA xT chunk -> LDS (swizzled rows); MFMA k/v; exp (softmax shift-invariant,
// no max pass); e/v round-trip through LDS (pitch 40); MFMA U += e @ v^T.
// Partials: U bf16, Z fp32 per block.
// NOTE: (512,2) not (512,4) — min-waves 4 caps VGPR at 128 and the ~140-reg
// live state spills to scratch (round-3: 170 MB WRITE_SIZE, 2x regression).
// ---------------------------------------------------------------------------
__global__ __launch_bounds__(512, 2) void k1_kv(float* __restrict__ ws) {
  // xs: 64 rows * 256 ushort = [0,16384); e/v overlay: 4 heads * 5120 = 20480
  __shared__ unsigned short lds[20480];

  const int tid = threadIdx.x;
  const int w = tid >> 6, lane = tid & 63, q = lane >> 4, cl = lane & 15;
  const int h = w >> 1, type = w & 1;
  const int bi = blockIdx.x;  // 512 = 8 b * 64 chunks
  const int b = bi >> 6, chunk = bi & 63;
  const int t0 = chunk * 128;
  const unsigned short* xT =
      (const unsigned short*)(ws + OFF_XT) + (size_t)b * TT * 256;
  const unsigned short* wkv =
      (const unsigned short*)(ws + OFF_WKV) + (size_t)((h * 2 + type) * 64) * 256;
  unsigned short* ekb = &lds[h * 5120];         // ek[64][40]
  unsigned short* vbb = &lds[h * 5120 + 2560];  // v [64][40]

  v4f Uacc[2][4];
#pragma unroll
  for (int i = 0; i < 2; ++i)
#pragma unroll
    for (int j = 0; j < 4; ++j) Uacc[i][j] = (v4f){0.f, 0.f, 0.f, 0.f};
  float zacc[4][4];
#pragma unroll
  for (int i = 0; i < 4; ++i)
#pragma unroll
    for (int j = 0; j < 4; ++j) zacc[i][j] = 0.f;

  for (int sub = 0; sub < 2; ++sub) {
    // ---- async stage 64 rows x 512 B: 32 pair-instructions, 4 per wave ----
    {
      const unsigned short* xsrc = xT + (size_t)(t0 + sub * 64) * 256 + lane * 8;
#pragma unroll
      for (int i = 0; i < 4; ++i) {
        const int p = w * 4 + i;
        ldscpy16(&lds[p * 512], xsrc + p * 512);
      }
    }
    __syncthreads();  // drains DMA + protects e/v region reuse

    // ---- phase A: rows = this wave's 64 k- or v-rows, cols = 64 t ----
    v4f acc[4][4];
#pragma unroll
    for (int i = 0; i < 4; ++i)
#pragma unroll
      for (int j = 0; j < 4; ++j) acc[i][j] = (v4f){0.f, 0.f, 0.f, 0.f};
#pragma unroll
    for (int ks = 0; ks < 8; ++ks) {
      v8s af[4], bfu[4];
#pragma unroll
      for (int rt = 0; rt < 4; ++rt)
        af[rt] = *(const v8s*)(wkv + (size_t)(rt * 16 + cl) * 256 + ks * 32 + q * 8);
#pragma unroll
      for (int ct = 0; ct < 4; ++ct) {
        const int t = ct * 16 + cl;
        bfu[ct] = *(const v8s*)&lds[t * 256 + (((ks * 4 + q) ^ (t & 7)) * 8)];
      }
#pragma unroll
      for (int rt = 0; rt < 4; ++rt)
#pragma unroll
        for (int ct = 0; ct < 4; ++ct)
          acc[rt][ct] = MFMA(af[rt], bfu[ct], acc[rt][ct]);
    }
    __syncthreads();  // all waves done with xs; e/v buffers overlay it

    // ---- phase B: two 32-t halves through LDS (pitch 40) ----
#pragma unroll
    for (int hp = 0; hp < 2; ++hp) {
      if (type == 0) {
#pragma unroll
        for (int rt = 0; rt < 4; ++rt)
#pragma unroll
          for (int cc = 0; cc < 2; ++cc) {
            const int ct = hp * 2 + cc;
#pragma unroll
            for (int reg = 0; reg < 4; ++reg) {
              const float e = __expf(acc[rt][ct][reg]);
              zacc[rt][reg] += e;
              ekb[(rt * 16 + q * 4 + reg) * 40 + cc * 16 + cl] = f2bf(e);
            }
          }
      } else {
#pragma unroll
        for (int rt = 0; rt < 4; ++rt)
#pragma unroll
          for (int cc = 0; cc < 2; ++cc) {
            const int ct = hp * 2 + cc;
#pragma unroll
            for (int reg = 0; reg < 4; ++reg)
              vbb[(rt * 16 + q * 4 + reg) * 40 + cc * 16 + cl] =
                  f2bf(acc[rt][ct][reg]);
          }
      }
      __syncthreads();  // head's wave pair exchanges e/v
      {
        const int du0 = type * 32;  // k-wave: U rows 0..31, v-wave: 32..63
        v8s afu[2], bfu[4];
#pragma unroll
        for (int ur = 0; ur < 2; ++ur)
          afu[ur] = *(const v8s*)&ekb[(du0 + ur * 16 + cl) * 40 + q * 8];
#pragma unroll
        for (int uc = 0; uc < 4; ++uc)
          bfu[uc] = *(const v8s*)&vbb[(uc * 16 + cl) * 40 + q * 8];
#pragma unroll
        for (int ur = 0; ur < 2; ++ur)
#pragma unroll
          for (int uc = 0; uc < 4; ++uc)
            Uacc[ur][uc] = MFMA(afu[ur], bfu[uc], Uacc[ur][uc]);
      }
      __syncthreads();  // half-1 / next sub will overwrite buffers
    }
  }

  // ---- Z: butterfly over the 16 col-lanes, store from cl==0 ----
  if (type == 0) {
#pragma unroll
    for (int m = 1; m < 16; m <<= 1)
#pragma unroll
      for (int rt = 0; rt < 4; ++rt)
#pragma unroll
        for (int reg = 0; reg < 4; ++reg)
          zacc[rt][reg] += __shfl_xor(zacc[rt][reg], m, 64);
    if (cl == 0) {
      for (int rt = 0; rt < 4; ++rt)
        for (int reg = 0; reg < 4; ++reg)
          ws[OFF_ZPART + (size_t)bi * 256 + h * 64 + rt * 16 + q * 4 + reg] =
              zacc[rt][reg];
    }
  }
  // ---- U partial store (bf16) ----
  unsigned short* Up =
      (unsigned short*)(ws + OFF_UPART) + (size_t)bi * 16384 + h * 4096;
#pragma unroll
  for (int ur = 0; ur < 2; ++ur)
#pragma unroll
    for (int uc = 0; uc < 4; ++uc)
#pragma unroll
      for (int reg = 0; reg < 4; ++reg)
        Up[(type * 32 + ur * 16 + q * 4 + reg) * 64 + uc * 16 + cl] =
            f2bf(Uacc[ur][uc][reg]);
}

// ---------------------------------------------------------------------------
// k2: reduce 64 partial blocks per batch; kv = U / Z[d].
// ---------------------------------------------------------------------------
__global__ void k2_reduce_kv(float* __restrict__ ws) {
  const int bi = blockIdx.x;  // 0..511
  const int bh = bi >> 4, j = bi & 15;
  const int b = bh >> 2, h = bh & 3;
  const int tid = threadIdx.x;

  __shared__ float zinv[64];
  if (tid < 64) {
    float z = 0.f;
    for (int cb = 0; cb < 64; ++cb)
      z += ws[OFF_ZPART + (size_t)(b * 64 + cb) * 256 + h * 64 + tid];
    zinv[tid] = 1.0f / z;
  }
  __syncthreads();

  const int idx = j * 256 + tid;  // 0..4095 in (b,h)
  const int d = idx >> 6;
  const unsigned short* up = (const unsigned short*)(ws + OFF_UPART);
  float s = 0.f;
  for (int cb = 0; cb < 64; ++cb)
    s += bf2f(up[(size_t)(b * 64 + cb) * 16384 + h * 4096 + idx]);
  ws[OFF_KV + (size_t)(b * 4 + h) * 4096 + idx] = s * zinv[d];
}

// ---------------------------------------------------------------------------
// k3a: P^T[b][c][h*64+e] = sum_d kv[b,h,d,e] * Wq[h*192+d][c]  (bf16)
// ---------------------------------------------------------------------------
__global__ void k3a_P(const float* __restrict__ Wpre, float* __restrict__ ws) {
  const int bi = blockIdx.x;  // b*256 + he
  const int b = bi >> 8, he = bi & 255;
  const int h = he >> 6, e = he & 63;
  const int c = threadIdx.x;
  const float* kvp = ws + OFF_KV + (size_t)(b * 4 + h) * 4096;
  float acc = 0.f;
#pragma unroll 8
  for (int d = 0; d < 64; ++d)
    acc += kvp[d * 64 + e] * Wpre[(size_t)(h * 192 + d) * 256 + c];
  ((unsigned short*)(ws + OFF_PT))[(size_t)b * 65536 + (size_t)c * 256 + he] =
      f2bf(acc);
}

// ---------------------------------------------------------------------------
// k3b: M[b][o][c] = scale * (Wproj @ P) via MFMA; grid = 8b x 4 c-groups.
// ---------------------------------------------------------------------------
__global__ __launch_bounds__(256, 2) void k3b_M(const float* __restrict__ scale,
                                                float* __restrict__ ws) {
  const int bi = blockIdx.x, b = bi >> 2, cg = bi & 3;
  const int tid = threadIdx.x, w = tid >> 6, lane = tid & 63, q = lane >> 4,
            cl = lane & 15;
  const unsigned short* wpj = (const unsigned short*)(ws + OFF_WPJ);
  const unsigned short* pt =
      (const unsigned short*)(ws + OFF_PT) + (size_t)b * 65536;
  v4f acc[4][4];
#pragma unroll
  for (int i = 0; i < 4; ++i)
#pragma unroll
    for (int j = 0; j < 4; ++j) acc[i][j] = (v4f){0.f, 0.f, 0.f, 0.f};
#pragma unroll
  for (int ks = 0; ks < 8; ++ks) {
    v8s af[4], bfu[4];
#pragma unroll
    for (int rt = 0; rt < 4; ++rt)
      af[rt] = *(const v8s*)(wpj + (size_t)(w * 64 + rt * 16 + cl) * 256 +
                             ks * 32 + q * 8);
#pragma unroll
    for (int ct = 0; ct < 4; ++ct)
      bfu[ct] = *(const v8s*)(pt + (size_t)(cg * 64 + ct * 16 + cl) * 256 +
                              ks * 32 + q * 8);
#pragma unroll
    for (int rt = 0; rt < 4; ++rt)
#pragma unroll
      for (int ct = 0; ct < 4; ++ct)
        acc[rt][ct] = MFMA(af[rt], bfu[ct], acc[rt][ct]);
  }
  const float s = scale[0];
  unsigned short* mbf = (unsigned short*)(ws + OFF_MBF);
#pragma unroll
  for (int rt = 0; rt < 4; ++rt)
#pragma unroll
    for (int ct = 0; ct < 4; ++ct)
#pragma unroll
      for (int reg = 0; reg < 4; ++reg) {
        const int o = w * 64 + rt * 16 + q * 4 + reg;
        const int c = cg * 64 + ct * 16 + cl;
        mbf[((size_t)b * 256 + o) * 256 + c] = f2bf(s * acc[rt][ct][reg]);
      }
}

// ---------------------------------------------------------------------------
// k4: out = LN_C( M@x + scale*b_proj + x ) * gamma + beta. DMA xT staging,
// MFMA, fused LN. Grid: 8b x 128 chunks of 64 t; 4 waves. (256,2): min-waves 4
// risks the same spill as k1 (acc tile ~130 VGPR live).
// ---------------------------------------------------------------------------
__global__ __launch_bounds__(256, 2) void k4_proj_ln(
    const float* __restrict__ bproj, const float* __restrict__ scale,
    const float* __restrict__ gamma, const float* __restrict__ beta,
    const float* __restrict__ ws, float* __restrict__ out) {
  __shared__ unsigned short xs[16384];  // [64 t][256 c] (rows XOR-swizzled)
  __shared__ float red1[256], red2[256], muA[64], rsA[64];
  const int bi = blockIdx.x, b = bi >> 7, tc = bi & 127;
  const int tg0 = tc * 64;
  const int tid = threadIdx.x, w = tid >> 6, lane = tid & 63, q = lane >> 4,
            cl = lane & 15;

  // async stage xT[tg0..+64)[*] -> xs: 32 pair-instructions, 8 per wave
  {
    const unsigned short* xsrc = (const unsigned short*)(ws + OFF_XT) +
                                 ((size_t)b * TT + tg0) * 256 + lane * 8;
#pragma unroll
    for (int i = 0; i < 8; ++i) {
      const int p = w * 8 + i;
      ldscpy16(&xs[p * 512], xsrc + p * 512);
    }
  }
  __syncthreads();

  const unsigned short* mbf =
      (const unsigned short*)(ws + OFF_MBF) + (size_t)b * 65536;
  v4f acc[4][4];
#pragma unroll
  for (int i = 0; i < 4; ++i)
#pragma unroll
    for (int j = 0; j < 4; ++j) acc[i][j] = (v4f){0.f, 0.f, 0.f, 0.f};
#pragma unroll
  for (int ks = 0; ks < 8; ++ks) {
    v8s af[4], bfu[4];
#pragma unroll
    for (int rt = 0; rt < 4; ++rt)
      af[rt] = *(const v8s*)(mbf + (size_t)(w * 64 + rt * 16 + cl) * 256 +
                             ks * 32 + q * 8);
#pragma unroll
    for (int ct = 0; ct < 4; ++ct) {
      const int t = ct * 16 + cl;
      bfu[ct] = *(const v8s*)&xs[t * 256 + (((ks * 4 + q) ^ (t & 7)) * 8)];
    }
#pragma unroll
    for (int rt = 0; rt < 4; ++rt)
#pragma unroll
      for (int ct = 0; ct < 4; ++ct)
        acc[rt][ct] = MFMA(af[rt], bfu[ct], acc[rt][ct]);
  }

  // y = ctx_proj + scale*b_proj + residual (residual from bf16 xs, swizzled)
  const float s = scale[0];
#pragma unroll
  for (int rt = 0; rt < 4; ++rt)
#pragma unroll
    for (int reg = 0; reg < 4; ++reg) {
      const int o = w * 64 + rt * 16 + q * 4 + reg;
      const float sb = s * bproj[o];
#pragma unroll
      for (int ct = 0; ct < 4; ++ct) {
        const int tl = ct * 16 + cl;
        acc[rt][ct][reg] +=
            sb + bf2f(xs[tl * 256 + (((o >> 3) ^ (tl & 7)) * 8) + (o & 7)]);
      }
    }

  // LN sums over C: per-lane 16 rows -> butterfly over q -> cross-wave LDS
#pragma unroll
  for (int ct = 0; ct < 4; ++ct) {
    float s1 = 0.f, s2 = 0.f;
#pragma unroll
    for (int rt = 0; rt < 4; ++rt)
#pragma unroll
      for (int reg = 0; reg < 4; ++reg) {
        const float v = acc[rt][ct][reg];
        s1 += v;
        s2 += v * v;
      }
    s1 += __shfl_xor(s1, 16, 64);
    s1 += __shfl_xor(s1, 32, 64);
    s2 += __shfl_xor(s2, 16, 64);
    s2 += __shfl_xor(s2, 32, 64);
    if (q == 0) {
      red1[w * 64 + ct * 16 + cl] = s1;
      red2[w * 64 + ct * 16 + cl] = s2;
    }
  }
  __syncthreads();
  if (tid < 64) {
    const float s1 = red1[tid] + red1[64 + tid] + red1[128 + tid] + red1[192 + tid];
    const float s2 = red2[tid] + red2[64 + tid] + red2[128 + tid] + red2[192 + tid];
    const float mu = s1 * (1.f / 256.f);
    const float var = s2 * (1.f / 256.f) - mu * mu;
    muA[tid] = mu;
    rsA[tid] = rsqrtf(var + EPSF);
  }
  __syncthreads();

  float* ob = out + (size_t)b * (CC * TT) + tg0;
#pragma unroll
  for (int rt = 0; rt < 4; ++rt)
#pragma unroll
    for (int reg = 0; reg < 4; ++reg) {
      const int o = w * 64 + rt * 16 + q * 4 + reg;
      const float g = gamma[o], bt = beta[o];
#pragma unroll
      for (int ct = 0; ct < 4; ++ct) {
        const int tl = ct * 16 + cl;
        ob[(size_t)o * TT + tl] = (acc[rt][ct][reg] - muA[tl]) * rsA[tl] * g + bt;
      }
    }
}

// ---------------------------------------------------------------------------
extern "C" void kernel_launch(void* const* d_in, const int* in_sizes, int n_in,
                              void* d_out, int out_size, void* d_ws,
                              size_t ws_size, hipStream_t stream) {
  (void)in_sizes; (void)n_in; (void)out_size; (void)ws_size;
  const float* x = (const float*)d_in[0];
  const float* Wpre = (const float*)d_in[1];
  const float* Wproj = (const float*)d_in[2];
  const float* bproj = (const float*)d_in[3];
  const float* scale = (const float*)d_in[4];
  const float* gamma = (const float*)d_in[5];
  const float* beta = (const float*)d_in[6];
  float* out = (float*)d_out;
  float* ws = (float*)d_ws;

  hipLaunchKernelGGL(kT_transpose, dim3(4096), dim3(256), 0, stream, x, ws);
  hipLaunchKernelGGL(k0_pack, dim3(768), dim3(256), 0, stream, Wpre, Wproj, ws);
  hipLaunchKernelGGL(k1_kv, dim3(512), dim3(512), 0, stream, ws);
  hipLaunchKernelGGL(k2_reduce_kv, dim3(512), dim3(256), 0, stream, ws);
  hipLaunchKernelGGL(k3a_P, dim3(BB * 256), dim3(256), 0, stream, Wpre, ws);
  hipLaunchKernelGGL(k3b_M, dim3(32), dim3(256), 0, stream, scale, ws);
  hipLaunchKernelGGL(k4_proj_ln, dim3(BB * 128), dim3(256), 0, stream, bproj,
                     scale, gamma, beta, ws, out);
}